// Round 3
// baseline (127.061 us; speedup 1.0000x reference)
//
#include <hip/hip_runtime.h>
#include <hip/hip_bf16.h>

typedef __attribute__((ext_vector_type(8)))  short  short8;
typedef __attribute__((ext_vector_type(4)))  float  f32x4;
typedef __attribute__((ext_vector_type(16))) float  f32x16;

#define DEVINL static __device__ __forceinline__

constexpr int BATCH = 8;
constexpr int SEQ   = 4096;
constexpr int EMB   = 256;
constexpr int HD    = 128;

// (1/sqrt(HD)) * log2(e): folded into Q at projection time
#define CSCALE 0.1275174475f

DEVINL unsigned cvt_pk_bf16(float lo, float hi) {
  unsigned r;
  asm("v_cvt_pk_bf16_f32 %0, %1, %2" : "=v"(r) : "v"(lo), "v"(hi));
  return r;
}

DEVINL void permswap32(unsigned &a, unsigned &b) {
  asm("v_permlane32_swap_b32 %0, %1" : "+v"(a), "+v"(b));
}

DEVINL short8 mk_frag(unsigned w0, unsigned w1, unsigned w2, unsigned w3) {
  union { unsigned u[4]; short8 s; } t;
  t.u[0] = w0; t.u[1] = w1; t.u[2] = w2; t.u[3] = w3;
  return t.s;
}

// ---------------------------------------------------------------------------
// Kernel 0: convert the three weight matrices to bf16 once.
// ---------------------------------------------------------------------------
__global__ __launch_bounds__(256) void wconv_kernel(
    const float* __restrict__ Wq, const float* __restrict__ Wk,
    const float* __restrict__ Wv, __hip_bfloat16* __restrict__ Wb)
{
  const int i = blockIdx.x * 256 + threadIdx.x;
  const int which = i >> 13;
  const int off = (i & 8191) << 2;
  const float* W = which == 0 ? Wq : which == 1 ? Wk : Wv;
  float4 f = *(const float4*)(W + off);
  unsigned lo = cvt_pk_bf16(f.x, f.y), hi = cvt_pk_bf16(f.z, f.w);
  unsigned long long pk = ((unsigned long long)hi << 32) | (unsigned long long)lo;
  *(unsigned long long*)(Wb + (size_t)which * 32768 + off) = pk;
}

// ---------------------------------------------------------------------------
// Kernel 1: one-pass QKV projection (unchanged from round 2).
// ---------------------------------------------------------------------------
__global__ __launch_bounds__(256) void qkv_proj_kernel(
    const float* __restrict__ X, const __hip_bfloat16* __restrict__ Wb,
    const float* __restrict__ bq, const float* __restrict__ bk,
    const float* __restrict__ bv,
    __hip_bfloat16* __restrict__ Qw, __hip_bfloat16* __restrict__ Kw,
    __hip_bfloat16* __restrict__ Vt)
{
  alignas(16) __shared__ char sT[128 * 128];

  const int m0   = blockIdx.x * 64;
  const int tid  = threadIdx.x;
  const int wid  = tid >> 6;
  const int lane = tid & 63;
  const int wr   = wid >> 1, wc = wid & 1;
  const int l15  = lane & 15, l4 = lane >> 4;

  f32x4 acc[3][2][4];
#pragma unroll
  for (int w = 0; w < 3; ++w)
#pragma unroll
    for (int qt = 0; qt < 2; ++qt)
#pragma unroll
      for (int nt = 0; nt < 4; ++nt)
#pragma unroll
        for (int r = 0; r < 4; ++r) acc[w][qt][nt][r] = 0.f;

  const int arow = m0 + wr * 32 + l15;
  const int hrow = wc * 64 + l15;

#pragma unroll
  for (int es = 0; es < 8; ++es) {
    const int k0 = es * 32 + l4 * 8;
    short8 af[2];
#pragma unroll
    for (int qt = 0; qt < 2; ++qt) {
      const float* src = X + (size_t)(arow + qt * 16) * EMB + k0;
      float4 f0 = *(const float4*)(src);
      float4 f1 = *(const float4*)(src + 4);
      af[qt] = mk_frag(cvt_pk_bf16(f0.x, f0.y), cvt_pk_bf16(f0.z, f0.w),
                       cvt_pk_bf16(f1.x, f1.y), cvt_pk_bf16(f1.z, f1.w));
    }
#pragma unroll
    for (int w = 0; w < 3; ++w) {
      short8 bf[4];
#pragma unroll
      for (int nt = 0; nt < 4; ++nt)
        bf[nt] = *(const short8*)(Wb + (size_t)w * 32768 +
                                  (size_t)(hrow + nt * 16) * EMB + k0);
#pragma unroll
      for (int qt = 0; qt < 2; ++qt)
#pragma unroll
        for (int nt = 0; nt < 4; ++nt)
          acc[w][qt][nt] = __builtin_amdgcn_mfma_f32_16x16x32_bf16(
              af[qt], bf[nt], acc[w][qt][nt], 0, 0, 0);
    }
  }

#pragma unroll
  for (int w = 0; w < 2; ++w) {
    __hip_bfloat16* dst = w ? Kw : Qw;
    const float* bia = w ? bk : bq;
    const float scale = w ? 1.0f : CSCALE;
#pragma unroll
    for (int qt = 0; qt < 2; ++qt)
#pragma unroll
      for (int nt = 0; nt < 4; ++nt) {
        const int h = wc * 64 + nt * 16 + l15;
        const float bb = bia[h];
        const int srow = m0 + wr * 32 + qt * 16 + l4 * 4;
#pragma unroll
        for (int r = 0; r < 4; ++r)
          dst[(size_t)(srow + r) * HD + h] =
              __float2bfloat16((acc[w][qt][nt][r] + bb) * scale);
      }
  }

#pragma unroll
  for (int qt = 0; qt < 2; ++qt)
#pragma unroll
    for (int nt = 0; nt < 4; ++nt) {
      const int h = wc * 64 + nt * 16 + l15;
      const float bb = bv[h];
      const int s_rel = wr * 32 + qt * 16 + l4 * 4;
      unsigned w0 = cvt_pk_bf16(acc[2][qt][nt][0] + bb, acc[2][qt][nt][1] + bb);
      unsigned w1 = cvt_pk_bf16(acc[2][qt][nt][2] + bb, acc[2][qt][nt][3] + bb);
      unsigned long long pk = ((unsigned long long)w1 << 32) | (unsigned long long)w0;
      *(unsigned long long*)(sT + h * 128 + ((s_rel * 2) ^ ((h & 7) << 4))) = pk;
    }
  __syncthreads();
  const int bi = m0 >> 12;
  const int s_base = m0 & (SEQ - 1);
#pragma unroll
  for (int p = 0; p < 4; ++p) {
    const int idx = p * 256 + tid;
    const int h = idx >> 3, slot = idx & 7;
    short8 v = *(const short8*)(sT + h * 128 + ((slot * 16) ^ ((h & 7) << 4)));
    *(short8*)(Vt + ((size_t)bi * HD + h) * SEQ + s_base + slot * 8) = v;
  }
}

// ---------------------------------------------------------------------------
// Kernel 2: flash attention, 512 thr (8 waves), grid 256 (1 block/CU).
// Same memory structure as round 2 (0-conflict LDS, reg-staged prefetch).
// NEW: both 32-k chunks of a tile batched -> two independent QK MFMA chains
// interleaved; single max/rescale per 64-kv tile; exp/cvt(c1) overlaps PV(c0).
// ---------------------------------------------------------------------------
__global__ __launch_bounds__(512, 2) void fused_attn_kernel(
    const __hip_bfloat16* __restrict__ Qw,
    const __hip_bfloat16* __restrict__ Kw,
    const __hip_bfloat16* __restrict__ Vt,
    float* __restrict__ out)
{
  alignas(16) __shared__ char smem[100352];
  float* sm_st = (float*)(smem + 98304);
  float* sl_st = (float*)(smem + 99328);

  const int tid  = threadIdx.x;
  const int wid  = tid >> 6;
  const int lane = tid & 63;
  const int l31  = lane & 31;
  const int hi   = lane >> 5;
  const int qg   = wid & 3;
  const int hw   = wid >> 2;

  const int b  = blockIdx.x & 7;
  const int q0 = (blockIdx.x >> 3) * 128;
  const int qrow = q0 + qg * 32 + l31;

  const __hip_bfloat16* Qp = Qw + ((size_t)b * SEQ + qrow) * HD;
  const __hip_bfloat16* Kg = Kw + (size_t)b * SEQ * HD;
  const __hip_bfloat16* Vg = Vt + (size_t)b * HD * SEQ;

  char* sK = smem + hw * 16384;
  char* sV = smem + 32768 + hw * 32768;

  short8 qf[8];
#pragma unroll
  for (int es = 0; es < 8; ++es)
    qf[es] = *(const short8*)(Qp + es * 16 + hi * 8);

  f32x16 oacc[4];
#pragma unroll
  for (int dt = 0; dt < 4; ++dt)
#pragma unroll
    for (int r = 0; r < 16; ++r) oacc[dt][r] = 0.f;

  float m = -1e30f, l = 0.f;

  const int hs = tid >> 8;
  const int st = tid & 255;
  const int tK_r = st >> 4, tK_cb = (st & 15) * 16;
  const int tV_d = st >> 3, tV_cb = (st & 7) * 16;
  char* wKp = smem + hs * 16384;
  char* wVp = smem + 32768 + hs * 32768;

  short8 rk[4], rv[4];
  {
    const int kb = hs * 64;
#pragma unroll
    for (int p = 0; p < 4; ++p) {
      rk[p] = *(const short8*)(Kg + (size_t)(kb + p * 16 + tK_r) * HD + (tK_cb >> 1));
      rv[p] = *(const short8*)(Vg + (size_t)(p * 32 + tV_d) * SEQ + kb + (tV_cb >> 1));
    }
  }

  const int NTH = SEQ / 64 / 2;

  // per-lane read keys/rows (invariant)
  const int kr0 = l31, kr1 = 32 + l31;
  const unsigned key0 = (unsigned)((kr0 & 15) << 4);
  const unsigned key1 = (unsigned)((kr1 & 15) << 4);

  for (int t = 0; t < NTH; ++t) {
    __syncthreads();
#pragma unroll
    for (int p = 0; p < 4; ++p) {
      const int r = p * 16 + tK_r;
      *(short8*)(wKp + r * 256 + (tK_cb ^ ((r & 15) << 4))) = rk[p];
      const int d = p * 32 + tV_d;
      *(short8*)(wVp + d * 256 + (tV_cb ^ ((d & 15) << 4))) = rv[p];
    }
    __syncthreads();

    if (t + 1 < NTH) {
      const int kb = (2 * (t + 1) + hs) * 64;
#pragma unroll
      for (int p = 0; p < 4; ++p) {
        rk[p] = *(const short8*)(Kg + (size_t)(kb + p * 16 + tK_r) * HD + (tK_cb >> 1));
        rv[p] = *(const short8*)(Vg + (size_t)(p * 32 + tV_d) * SEQ + kb + (tV_cb >> 1));
      }
    }

    // ---- QK: two independent interleaved MFMA chains (chunks 0 and 1) ----
    f32x16 s0, s1;
#pragma unroll
    for (int r = 0; r < 16; ++r) { s0[r] = 0.f; s1[r] = 0.f; }
    __builtin_amdgcn_s_setprio(1);
#pragma unroll
    for (int es = 0; es < 8; ++es) {
      const int cb = es * 32 + hi * 16;
      short8 ka0 = *(const short8*)(sK + kr0 * 256 + (cb ^ key0));
      short8 ka1 = *(const short8*)(sK + kr1 * 256 + (cb ^ key1));
      s0 = __builtin_amdgcn_mfma_f32_32x32x16_bf16(ka0, qf[es], s0, 0, 0, 0);
      s1 = __builtin_amdgcn_mfma_f32_32x32x16_bf16(ka1, qf[es], s1, 0, 0, 0);
    }
    __builtin_amdgcn_s_setprio(0);

    // ---- combined max over both chunks (32 values) ----
    float mx[8];
#pragma unroll
    for (int r = 0; r < 8; ++r)
      mx[r] = fmaxf(fmaxf(s0[r], s0[r + 8]), fmaxf(s1[r], s1[r + 8]));
    float m4a = fmaxf(fmaxf(mx[0], mx[1]), fmaxf(mx[2], mx[3]));
    float m4b = fmaxf(fmaxf(mx[4], mx[5]), fmaxf(mx[6], mx[7]));
    float cmax = fmaxf(m4a, m4b);
    cmax = fmaxf(cmax, __shfl_xor(cmax, 32, 64));

    if (!__all(cmax - m <= 8.0f)) {        // defer-max (THR=8, exp2 domain)
      const float newm = fmaxf(m, cmax);
      const float sc = __builtin_amdgcn_exp2f(m - newm);
#pragma unroll
      for (int dt = 0; dt < 4; ++dt)
#pragma unroll
        for (int r = 0; r < 16; ++r) oacc[dt][r] *= sc;
      l *= sc;
      m = newm;
    }

    // ---- chunk 0: exp + cvt + PV; chunk 1's exp/cvt overlaps PV(c0) ----
    float ls0 = 0.f, ls1 = 0.f, ls2 = 0.f, ls3 = 0.f;
#pragma unroll
    for (int r = 0; r < 4; ++r) {
      s0[r]      = __builtin_amdgcn_exp2f(s0[r] - m);
      s0[r + 4]  = __builtin_amdgcn_exp2f(s0[r + 4] - m);
      s0[r + 8]  = __builtin_amdgcn_exp2f(s0[r + 8] - m);
      s0[r + 12] = __builtin_amdgcn_exp2f(s0[r + 12] - m);
      ls0 += s0[r]; ls1 += s0[r + 4]; ls2 += s0[r + 8]; ls3 += s0[r + 12];
    }
    short8 pb0[2];
#pragma unroll
    for (int h2 = 0; h2 < 2; ++h2) {
      unsigned a0 = cvt_pk_bf16(s0[8 * h2 + 0], s0[8 * h2 + 1]);
      unsigned a1 = cvt_pk_bf16(s0[8 * h2 + 2], s0[8 * h2 + 3]);
      unsigned b0 = cvt_pk_bf16(s0[8 * h2 + 4], s0[8 * h2 + 5]);
      unsigned b1 = cvt_pk_bf16(s0[8 * h2 + 6], s0[8 * h2 + 7]);
      permswap32(a0, b0);
      permswap32(a1, b1);
      pb0[h2] = mk_frag(a0, a1, b0, b1);
    }

    __builtin_amdgcn_s_setprio(1);
#pragma unroll
    for (int ks = 0; ks < 2; ++ks)
#pragma unroll
      for (int dt = 0; dt < 4; ++dt) {
        const int vrow = dt * 32 + l31;
        const unsigned vkey = (unsigned)((vrow & 15) << 4);
        short8 va = *(const short8*)(sV + vrow * 256 + ((ks * 32 + hi * 16) ^ vkey));
        oacc[dt] = __builtin_amdgcn_mfma_f32_32x32x16_bf16(va, pb0[ks], oacc[dt], 0, 0, 0);
      }
    __builtin_amdgcn_s_setprio(0);

#pragma unroll
    for (int r = 0; r < 4; ++r) {
      s1[r]      = __builtin_amdgcn_exp2f(s1[r] - m);
      s1[r + 4]  = __builtin_amdgcn_exp2f(s1[r + 4] - m);
      s1[r + 8]  = __builtin_amdgcn_exp2f(s1[r + 8] - m);
      s1[r + 12] = __builtin_amdgcn_exp2f(s1[r + 12] - m);
      ls0 += s1[r]; ls1 += s1[r + 4]; ls2 += s1[r + 8]; ls3 += s1[r + 12];
    }
    short8 pb1[2];
#pragma unroll
    for (int h2 = 0; h2 < 2; ++h2) {
      unsigned a0 = cvt_pk_bf16(s1[8 * h2 + 0], s1[8 * h2 + 1]);
      unsigned a1 = cvt_pk_bf16(s1[8 * h2 + 2], s1[8 * h2 + 3]);
      unsigned b0 = cvt_pk_bf16(s1[8 * h2 + 4], s1[8 * h2 + 5]);
      unsigned b1 = cvt_pk_bf16(s1[8 * h2 + 6], s1[8 * h2 + 7]);
      permswap32(a0, b0);
      permswap32(a1, b1);
      pb1[h2] = mk_frag(a0, a1, b0, b1);
    }

    __builtin_amdgcn_s_setprio(1);
#pragma unroll
    for (int ks = 0; ks < 2; ++ks)
#pragma unroll
      for (int dt = 0; dt < 4; ++dt) {
        const int vrow = dt * 32 + l31;
        const unsigned vkey = (unsigned)((vrow & 15) << 4);
        short8 va = *(const short8*)(sV + vrow * 256 + ((64 + ks * 32 + hi * 16) ^ vkey));
        oacc[dt] = __builtin_amdgcn_mfma_f32_32x32x16_bf16(va, pb1[ks], oacc[dt], 0, 0, 0);
      }
    __builtin_amdgcn_s_setprio(0);

    l += (ls0 + ls1) + (ls2 + ls3);
  }

  // ---- flash merge of the two halves (wave w <-> w^4) ----
  const float ltot = l + __shfl_xor(l, 32, 64);
  if (hi == 0) { sm_st[wid * 32 + l31] = m; sl_st[wid * 32 + l31] = ltot; }
  __syncthreads();
  const int pw = wid ^ 4;
  const float m2 = sm_st[pw * 32 + l31];
  const float l2 = sl_st[pw * 32 + l31];
  const float M  = fmaxf(m, m2);
  const float aown = __builtin_amdgcn_exp2f(m - M);
  const float Ltot = ltot * aown + l2 * __builtin_amdgcn_exp2f(m2 - M);

  float* mb = (float*)smem + (size_t)qg * 4096;
  if (hw == 1) {
#pragma unroll
    for (int dt = 0; dt < 4; ++dt)
#pragma unroll
      for (int r = 0; r < 16; ++r) {
        const int d = dt * 32 + (r & 3) + 8 * (r >> 2) + 4 * hi;
        mb[d * 32 + l31] = oacc[dt][r] * aown;
      }
  }
  __syncthreads();
  if (hw == 0) {
    const float inv = 1.0f / Ltot;
    float* op = out + ((size_t)b * SEQ + qrow) * HD;
#pragma unroll
    for (int dt = 0; dt < 4; ++dt) {
#pragma unroll
      for (int rg = 0; rg < 4; ++rg) {
        const int d0 = dt * 32 + rg * 8 + hi * 4;
        float4 v;
        v.x = (oacc[dt][rg * 4 + 0] * aown + mb[(d0 + 0) * 32 + l31]) * inv;
        v.y = (oacc[dt][rg * 4 + 1] * aown + mb[(d0 + 1) * 32 + l31]) * inv;
        v.z = (oacc[dt][rg * 4 + 2] * aown + mb[(d0 + 2) * 32 + l31]) * inv;
        v.w = (oacc[dt][rg * 4 + 3] * aown + mb[(d0 + 3) * 32 + l31]) * inv;
        *(float4*)(op + d0) = v;
      }
    }
  }
}

// ---------------------------------------------------------------------------
extern "C" void kernel_launch(void* const* d_in, const int* in_sizes, int n_in,
                              void* d_out, int out_size, void* d_ws, size_t ws_size,
                              hipStream_t stream) {
  (void)in_sizes; (void)n_in; (void)out_size; (void)ws_size;
  const float* X  = (const float*)d_in[0];
  const float* Wk = (const float*)d_in[1];
  const float* bk = (const float*)d_in[2];
  const float* Wq = (const float*)d_in[3];
  const float* bq = (const float*)d_in[4];
  const float* Wv = (const float*)d_in[5];
  const float* bv = (const float*)d_in[6];
  float* out = (float*)d_out;

  __hip_bfloat16* Qw = (__hip_bfloat16*)d_ws;
  __hip_bfloat16* Kw = Qw + (size_t)BATCH * SEQ * HD;
  __hip_bfloat16* Vt = Kw + (size_t)BATCH * SEQ * HD;
  __hip_bfloat16* Wb = Vt + (size_t)BATCH * SEQ * HD;

  wconv_kernel<<<96, 256, 0, stream>>>(Wq, Wk, Wv, Wb);
  qkv_proj_kernel<<<BATCH * SEQ / 64, 256, 0, stream>>>(
      X, Wb, bq, bk, bv, Qw, Kw, Vt);
  fused_attn_kernel<<<BATCH * (SEQ / 128), 512, 0, stream>>>(Qw, Kw, Vt, out);
}